// Round 4
// baseline (784.459 us; speedup 1.0000x reference)
//
#include <hip/hip_runtime.h>
#include <math.h>

#define B_Q 1024
#define L_SEQ 128
#define D_EMB 256
#define NLAB 131072
#define LBL_ROWS 8192
#define NEG_ROWS 2048
#define W_ROWS 10240
#define CROW 320   // compact row: 64 poly + 256 prf
#define LSTN 84    // k_neg LDS row stride (16B-aligned; rows 1 apart -> bank phase 20)
#define WCH 256    // k_wstage columns per block
#define WNB 44     // k_wstage max staged rows per batch (Poisson lambda=19)
#define WLS 258    // k_wstage LDS row stride (even -> 8B-aligned float2)

__device__ __forceinline__ float wave_sum(float v) {
#pragma unroll
  for (int off = 32; off > 0; off >>= 1) v += __shfl_xor(v, off, 64);
  return v;
}

// sx: 256 per-head-normalized dims in LDS. t in [0,256). One compact row out.
__device__ __forceinline__ void slay_tail(const float* __restrict__ sx, int t,
                                          const float* __restrict__ anchT,
                                          const float* __restrict__ omega,
                                          float* __restrict__ outrow) {
  if (t < 64) {
    const int h = t >> 4, p = t & 15;
    const float* x = sx + h * 64;
    float d = 0.f;
#pragma unroll
    for (int dd = 0; dd < 64; dd++) d = fmaf(x[dd], anchT[dd * 16 + p], d);
    d = fminf(fmaxf(d, -1.0f), 1.0f);
    outrow[h * 16 + p] = d * d * 0.25f;
  }
  {
    const int r = t >> 7, h = (t >> 5) & 3;
    const float* x = sx + h * 64;
    const float* om = omega + (size_t)(t >> 5) * 2048 + (t & 31);
    float d = 0.f;
#pragma unroll
    for (int dd = 0; dd < 64; dd++) d = fmaf(x[dd], om[dd * 32], d);
    const float proj = d * 0.125f;
    const float s = r ? 1.70710592763316f : 0.29289307236691f;
    const float w = r ? 0.07322326809171f : 0.42677648190829f;
    float arg = proj * sqrtf(2.0f * s) - s;
    arg = fminf(fmaxf(arg, -20.0f), 20.0f);
    outrow[64 + t] = expf(arg) * (sqrtf(w) / sqrtf(32.000001f));
  }
}

// block 0: anchors. blocks 1..128: zero negparts (32*1024). 129..640: claim = -1.
__global__ __launch_bounds__(256) void k_prep(const float* __restrict__ anchors,
                                              float* __restrict__ anchT,
                                              float* __restrict__ negparts,
                                              int* __restrict__ claim) {
  const int t = threadIdx.x, bx = blockIdx.x;
  if (bx == 0) {
    if (t < 64) {
      for (int p = 0; p < 16; p++) {
        const float v = anchors[p * 64 + t];
        const float n = sqrtf(wave_sum(v * v));
        anchT[t * 16 + p] = v / n;
      }
    }
  } else if (bx <= 128) {
    negparts[(bx - 1) * 256 + t] = 0.f;
  } else {
    claim[(bx - 129) * 256 + t] = -1;
  }
}

// each needed row i claims its column j (plain store: duplicate-j races benign)
__global__ __launch_bounds__(256) void k_mark(const int* __restrict__ labels,
                                              const int* __restrict__ negidx,
                                              int* __restrict__ claim,
                                              int* __restrict__ jidx) {
  const int i = blockIdx.x * 256 + threadIdx.x;
  if (i >= W_ROWS) return;
  int j;
  if (i < LBL_ROWS) { j = labels[i]; if (j < 0) j = 0; }
  else               { j = negidx[i - LBL_ROWS]; }
  claim[j] = i;
  jidx[i] = j;
}

__global__ __launch_bounds__(256) void k_query(const int* __restrict__ indices,
                                               const float* __restrict__ mask,
                                               const float* __restrict__ embed,
                                               const float* __restrict__ anchT,
                                               const float* __restrict__ omega,
                                               float* __restrict__ qcomp) {
  const int b = blockIdx.x, t = threadIdx.x;
  const int wv = t >> 6, ln = t & 63;
  __shared__ int sidx[L_SEQ];
  __shared__ float smask[L_SEQ];
  __shared__ float4 spart[256];
  __shared__ float smsum[4];
  __shared__ float sx[256];
  if (t < L_SEQ) { sidx[t] = indices[b * L_SEQ + t]; smask[t] = mask[b * L_SEQ + t]; }
  __syncthreads();
  float4 acc = {0.f, 0.f, 0.f, 0.f};
  float msum = 0.f;
#pragma unroll 8
  for (int l = wv * 32; l < wv * 32 + 32; l++) {
    const float m = smask[l];
    msum += m;
    const float4 e = *(const float4*)(embed + (size_t)sidx[l] * D_EMB + ln * 4);
    acc.x = fmaf(e.x, m, acc.x); acc.y = fmaf(e.y, m, acc.y);
    acc.z = fmaf(e.z, m, acc.z); acc.w = fmaf(e.w, m, acc.w);
  }
  spart[wv * 64 + ln] = acc;
  if (ln == 0) smsum[wv] = msum;
  __syncthreads();
  const float* spf = (const float*)spart;
  float q = spf[t] + spf[256 + t] + spf[512 + t] + spf[768 + t];
  const float mt = smsum[0] + smsum[1] + smsum[2] + smsum[3];
  q /= fmaxf(mt, 1.0f);
  const float ss = wave_sum(q * q);  // wave == head
  sx[t] = q / fmaxf(sqrtf(ss), 1e-4f);
  __syncthreads();
  slay_tail(sx, t, anchT, omega, qcomp + (size_t)b * CROW);
}

// Stream kern coalesced; keep claimed columns in LDS; compute compact rows.
__global__ __launch_bounds__(256) void k_wstage(const float* __restrict__ kern,
                                                const int* __restrict__ claim,
                                                const float* __restrict__ anchT,
                                                const float* __restrict__ omega,
                                                float* __restrict__ wcomp) {
  __shared__ __align__(16) float sx[48 * WLS];  // 4 pad rows: prf reads up to row 47
  __shared__ float snorm[WNB * 4];
  __shared__ int lcol2a[WCH];
  __shared__ int lowner[WCH];
  __shared__ int scnt;
  const int tid = threadIdx.x;
  const int c0 = blockIdx.x * WCH;
  if (tid == 0) scnt = 0;
  lcol2a[tid] = -1;
  __syncthreads();
  const int owner = claim[c0 + tid];
  int mya = -1;
  if (owner >= 0) { mya = atomicAdd(&scnt, 1); lcol2a[tid] = mya; lowner[mya] = owner; }
  __syncthreads();
  const int cnt = scnt;
  float cs = 0.f;
  const size_t colbase = (size_t)(c0 + tid);

  for (int bs = 0; bs < cnt; bs += WNB) {
    const int nb = min(WNB, cnt - bs);
    __syncthreads();
    const int aloc = (mya >= bs && mya < bs + nb) ? (mya - bs) : -1;
    // coalesced stream of this column chunk; keep active columns
    for (int t = 0; t < 256; t += 8) {
      float v[8];
#pragma unroll
      for (int k = 0; k < 8; k++) v[k] = kern[(size_t)(t + k) * NLAB + colbase];
#pragma unroll
      for (int k = 0; k < 8; k++) cs += v[k];
      if (aloc >= 0) {
#pragma unroll
        for (int k = 0; k < 8; k++) sx[aloc * WLS + t + k] = v[k];
      }
    }
    __syncthreads();
    // per-(row,head) norms: 32 threads per row, octet shuffle-reduce
    for (int a = tid >> 5; a < nb; a += 8) {
      const int sub = tid & 31;
      const float* xp = sx + a * WLS + sub * 8;
      float ssum = 0.f;
#pragma unroll
      for (int e = 0; e < 8; e++) ssum = fmaf(xp[e], xp[e], ssum);
      ssum += __shfl_xor(ssum, 1, 64);
      ssum += __shfl_xor(ssum, 2, 64);
      ssum += __shfl_xor(ssum, 4, 64);
      if ((sub & 7) == 0) snorm[a * 4 + (sub >> 3)] = fmaxf(sqrtf(ssum), 1e-4f);
    }
    __syncthreads();
    for (int idx = tid; idx < nb * 256; idx += 256)
      sx[(idx >> 8) * WLS + (idx & 255)] /= snorm[(idx >> 8) * 4 + ((idx >> 6) & 3)];
    __syncthreads();
    // prf: thread=(r,h,m); omega element reused across 8 rows
    {
      const int h = (tid >> 5) & 3, r = tid >> 7;
      const float* om = omega + (size_t)(tid >> 5) * 2048 + (tid & 31);
      const float s = r ? 1.70710592763316f : 0.29289307236691f;
      const float w = r ? 0.07322326809171f : 0.42677648190829f;
      const float sc = sqrtf(2.0f * s);
      const float outs = sqrtf(w) / sqrtf(32.000001f);
      for (int rb = 0; rb < nb; rb += 8) {
        float acc[8] = {0.f, 0.f, 0.f, 0.f, 0.f, 0.f, 0.f, 0.f};
#pragma unroll
        for (int dd = 0; dd < 64; dd += 2) {
          const float o0 = om[dd * 32], o1 = om[dd * 32 + 32];
#pragma unroll
          for (int rr = 0; rr < 8; rr++) {
            const float2 xv = *(const float2*)(sx + (rb + rr) * WLS + h * 64 + dd);
            acc[rr] = fmaf(xv.x, o0, fmaf(xv.y, o1, acc[rr]));
          }
        }
#pragma unroll
        for (int rr = 0; rr < 8; rr++) {
          if (rb + rr < nb) {
            float arg = fminf(fmaxf(acc[rr] * 0.125f * sc - s, -20.f), 20.f);
            wcomp[(size_t)lowner[bs + rb + rr] * CROW + 64 + tid] = expf(arg) * outs;
          }
        }
      }
    }
    // poly: thread=(h,p,rowgroup)
    {
      const int hp = tid & 63, rg = tid >> 6;
      const int h = hp >> 4, p = hp & 15;
      for (int row = rg; row < nb; row += 4) {
        const float* x = sx + row * WLS + h * 64;
        float d = 0.f;
#pragma unroll
        for (int dd = 0; dd < 64; dd++) d = fmaf(x[dd], anchT[dd * 16 + p], d);
        d = fminf(fmaxf(d, -1.0f), 1.0f);
        wcomp[(size_t)lowner[bs + row] * CROW + h * 16 + p] = d * d * 0.25f;
      }
    }
  }
  if (cnt > 255) sx[0] = cs;  // reachable-but-harmless: forces the streaming loads
}

// duplicate rows copy their owner's compact row (one wave per row)
__global__ __launch_bounds__(256) void k_fix(const int* __restrict__ claim,
                                             const int* __restrict__ jidx,
                                             float* __restrict__ wcomp) {
  const int i = (blockIdx.x * 256 + threadIdx.x) >> 6;
  const int lane = threadIdx.x & 63;
  const int j = jidx[i];
  const int own = claim[j];
  if (own != i) {
#pragma unroll
    for (int l = 0; l < 5; l++)
      wcomp[(size_t)i * CROW + lane + 64 * l] = wcomp[(size_t)own * CROW + lane + 64 * l];
  }
}

// neg partial sums: grid (16 qtiles, 32 wtiles, 4 heads), 128 thr.
// Block: 64 q x 64 w x one h. Thread: 8q x 4w (strided rows), float4 k-chunks.
__global__ __launch_bounds__(128) void k_neg(const float* __restrict__ qcomp,
                                             const float* __restrict__ wcomp,
                                             float* __restrict__ negparts) {
  __shared__ __align__(16) float qt[64 * LSTN];
  __shared__ __align__(16) float wt[64 * LSTN];
  const int tid = threadIdx.x;
  const int qb0 = blockIdx.x * 64;
  const int wr0 = LBL_ROWS + blockIdx.y * 64;
  const int h = blockIdx.z;

  // stage 128 rows x 80 floats (this head's slice), 20 float4 per row
  for (int idx = tid; idx < 128 * 20; idx += 128) {
    const int row = idx / 20, c4 = idx % 20;
    int col, lcol;
    if (c4 < 4)       { col = h * 16 + c4 * 4;              lcol = c4 * 4; }
    else if (c4 < 12) { col = 64 + h * 32 + (c4 - 4) * 4;   lcol = 16 + (c4 - 4) * 4; }
    else              { col = 192 + h * 32 + (c4 - 12) * 4; lcol = 48 + (c4 - 12) * 4; }
    const bool isq = row < 64;
    const int grow = isq ? (qb0 + row) : (wr0 + row - 64);
    const float4 v = *(const float4*)((isq ? qcomp : wcomp) + (size_t)grow * CROW + col);
    *(float4*)((isq ? qt + row * LSTN : wt + (row - 64) * LSTN) + lcol) = v;
  }
  __syncthreads();

  const int qg = tid >> 4;   // 0..7 -> q rows qg + 8i
  const int wg = tid & 15;   // 0..15 -> w rows wg + 16j
  float pd[8][4] = {{0.f}}, pf[8][4] = {{0.f}};

#pragma unroll
  for (int kc = 0; kc < 4; kc++) {   // poly cols [0,16)
    float4 qv[8], wv[4];
#pragma unroll
    for (int i = 0; i < 8; i++) qv[i] = *(const float4*)(qt + (qg + 8 * i) * LSTN + kc * 4);
#pragma unroll
    for (int j = 0; j < 4; j++) wv[j] = *(const float4*)(wt + (wg + 16 * j) * LSTN + kc * 4);
#pragma unroll
    for (int i = 0; i < 8; i++)
#pragma unroll
      for (int j = 0; j < 4; j++) {
        pd[i][j] = fmaf(qv[i].x, wv[j].x, pd[i][j]);
        pd[i][j] = fmaf(qv[i].y, wv[j].y, pd[i][j]);
        pd[i][j] = fmaf(qv[i].z, wv[j].z, pd[i][j]);
        pd[i][j] = fmaf(qv[i].w, wv[j].w, pd[i][j]);
      }
  }
#pragma unroll
  for (int kc = 4; kc < 20; kc++) {  // prf cols [16,80) (r0||r1)
    float4 qv[8], wv[4];
#pragma unroll
    for (int i = 0; i < 8; i++) qv[i] = *(const float4*)(qt + (qg + 8 * i) * LSTN + kc * 4);
#pragma unroll
    for (int j = 0; j < 4; j++) wv[j] = *(const float4*)(wt + (wg + 16 * j) * LSTN + kc * 4);
#pragma unroll
    for (int i = 0; i < 8; i++)
#pragma unroll
      for (int j = 0; j < 4; j++) {
        pf[i][j] = fmaf(qv[i].x, wv[j].x, pf[i][j]);
        pf[i][j] = fmaf(qv[i].y, wv[j].y, pf[i][j]);
        pf[i][j] = fmaf(qv[i].z, wv[j].z, pf[i][j]);
        pf[i][j] = fmaf(qv[i].w, wv[j].w, pf[i][j]);
      }
  }

#pragma unroll
  for (int i = 0; i < 8; i++) {
    float acc = 0.f;
#pragma unroll
    for (int j = 0; j < 4; j++) acc += pd[i][j] * pf[i][j];
    acc += __shfl_xor(acc, 1, 64);
    acc += __shfl_xor(acc, 2, 64);
    acc += __shfl_xor(acc, 4, 64);
    acc += __shfl_xor(acc, 8, 64);
    if (wg == 0) atomicAdd(&negparts[blockIdx.y * B_Q + qb0 + qg + 8 * i], acc);
  }
}

__global__ __launch_bounds__(256) void k_pos(const float* __restrict__ qcomp,
                                             const float* __restrict__ wcomp,
                                             float* __restrict__ pos) {
  const int tid = threadIdx.x;
  const int g = blockIdx.x * 64 + (tid >> 2);
  const int h = tid & 3;
  const float* q = qcomp + (size_t)(g >> 3) * CROW;
  const float* w = wcomp + (size_t)g * CROW;
  float pd = 0.f, pf = 0.f;
#pragma unroll
  for (int c = 0; c < 4; c++) {
    const float4 qv = *(const float4*)(q + h * 16 + c * 4);
    const float4 wv = *(const float4*)(w + h * 16 + c * 4);
    pd += qv.x * wv.x + qv.y * wv.y + qv.z * wv.z + qv.w * wv.w;
  }
#pragma unroll
  for (int r = 0; r < 2; r++)
#pragma unroll
    for (int c = 0; c < 8; c++) {
      const float4 qv = *(const float4*)(q + 64 + r * 128 + h * 32 + c * 4);
      const float4 wv = *(const float4*)(w + 64 + r * 128 + h * 32 + c * 4);
      pf += qv.x * wv.x + qv.y * wv.y + qv.z * wv.z + qv.w * wv.w;
    }
  float sc = pd * pf;
  sc += __shfl_xor(sc, 1, 64);
  sc += __shfl_xor(sc, 2, 64);
  if (h == 0) pos[g] = sc;
}

__global__ __launch_bounds__(1024) void k_loss(const float* __restrict__ pos,
                                               const float* __restrict__ negparts,
                                               const float* __restrict__ lmask,
                                               float* __restrict__ out) {
  const int b = threadIdx.x;
  float lp[8];
  float possum = 0.f;
#pragma unroll
  for (int k = 0; k < 8; k++) { lp[k] = pos[b * 8 + k]; possum += lp[k]; }
  float negsum = 0.f;
#pragma unroll 8
  for (int c = 0; c < 32; c++) negsum += negparts[c * B_Q + b];
  const float Z = possum + negsum + 2.056e-5f;  // + 2056 * 1e-8
  const float logZ = logf(Z);
  float local = 0.f, lsum = 0.f;
#pragma unroll
  for (int k = 0; k < 8; k++) {
    const float lm = lmask[b * 8 + k];
    local += lm * (logf(lp[k] + 1e-8f) - logZ);
    lsum += lm;
  }
  local = wave_sum(local);
  lsum = wave_sum(lsum);
  __shared__ float r1[16], r2[16];
  const int wid = b >> 6;
  if ((b & 63) == 0) { r1[wid] = local; r2[wid] = lsum; }
  __syncthreads();
  if (b == 0) {
    float t1 = 0.f, t2 = 0.f;
    for (int wv = 0; wv < 16; wv++) { t1 += r1[wv]; t2 += r2[wv]; }
    out[0] = -t1 / (t2 + 1e-6f);
  }
}

extern "C" void kernel_launch(void* const* d_in, const int* in_sizes, int n_in,
                              void* d_out, int out_size, void* d_ws, size_t ws_size,
                              hipStream_t stream) {
  const int* indices  = (const int*)d_in[0];
  const float* mask   = (const float*)d_in[1];
  const int* labels   = (const int*)d_in[2];
  const float* lmask  = (const float*)d_in[3];
  const int* negidx   = (const int*)d_in[4];
  const float* embed  = (const float*)d_in[5];
  const float* kern   = (const float*)d_in[6];
  const float* omega  = (const float*)d_in[7];
  const float* anchors= (const float*)d_in[8];
  float* out = (float*)d_out;

  float* ws = (float*)d_ws;
  float* anchT    = ws;                            // 1024
  float* qcomp    = anchT + 1024;                  // 1024*320
  float* wcomp    = qcomp + (size_t)B_Q * CROW;    // 10240*320
  float* pos      = wcomp + (size_t)W_ROWS * CROW; // 8192
  float* negparts = pos + LBL_ROWS;                // 32*1024
  int*   claim    = (int*)(negparts + 32 * B_Q);   // 131072
  int*   jidx     = claim + NLAB;                  // 10240

  k_prep<<<641, 256, 0, stream>>>(anchors, anchT, negparts, claim);
  k_mark<<<40, 256, 0, stream>>>(labels, negidx, claim, jidx);
  k_query<<<B_Q, 256, 0, stream>>>(indices, mask, embed, anchT, omega, qcomp);
  k_wstage<<<NLAB / WCH, 256, 0, stream>>>(kern, claim, anchT, omega, wcomp);
  k_fix<<<W_ROWS / 4, 256, 0, stream>>>(claim, jidx, wcomp);
  k_neg<<<dim3(16, 32, 4), 128, 0, stream>>>(qcomp, wcomp, negparts);
  k_pos<<<128, 256, 0, stream>>>(qcomp, wcomp, pos);
  k_loss<<<1, 1024, 0, stream>>>(pos, negparts, lmask, out);
}

// Round 5
// 358.314 us; speedup vs baseline: 2.1893x; 2.1893x over previous
//
#include <hip/hip_runtime.h>
#include <math.h>

#define B_Q 1024
#define L_SEQ 128
#define D_EMB 256
#define NLAB 131072
#define LBL_ROWS 8192
#define NEG_ROWS 2048
#define W_ROWS 10240
#define CROW 320   // compact row: 64 poly + 256 prf
#define LST 82     // k_neg LDS row stride
#define RPB 8      // k_wrows rows per block

__device__ __forceinline__ float wave_sum(float v) {
#pragma unroll
  for (int off = 32; off > 0; off >>= 1) v += __shfl_xor(v, off, 64);
  return v;
}

// sx: 256 per-head-normalized dims in LDS. t in [0,256). One compact row out.
__device__ __forceinline__ void slay_tail(const float* __restrict__ sx, int t,
                                          const float* __restrict__ anchT,
                                          const float* __restrict__ omega,
                                          float* __restrict__ outrow) {
  if (t < 64) {
    const int h = t >> 4, p = t & 15;
    const float* x = sx + h * 64;
    float d = 0.f;
#pragma unroll
    for (int dd = 0; dd < 64; dd++) d = fmaf(x[dd], anchT[dd * 16 + p], d);
    d = fminf(fmaxf(d, -1.0f), 1.0f);
    outrow[h * 16 + p] = d * d * 0.25f;
  }
  {
    const int r = t >> 7, h = (t >> 5) & 3;
    const float* x = sx + h * 64;
    const float* om = omega + (size_t)(t >> 5) * 2048 + (t & 31);
    float d = 0.f;
#pragma unroll
    for (int dd = 0; dd < 64; dd++) d = fmaf(x[dd], om[dd * 32], d);
    const float proj = d * 0.125f;
    const float s = r ? 1.70710592763316f : 0.29289307236691f;
    const float w = r ? 0.07322326809171f : 0.42677648190829f;
    float arg = proj * sqrtf(2.0f * s) - s;
    arg = fminf(fmaxf(arg, -20.0f), 20.0f);
    outrow[64 + t] = expf(arg) * (sqrtf(w) / sqrtf(32.000001f));
  }
}

// block 0: anchors. 1..256: zero negparts (64*1024). 257..264: zero hist (2048).
__global__ __launch_bounds__(256) void k_prep(const float* __restrict__ anchors,
                                              float* __restrict__ anchT,
                                              float* __restrict__ negparts,
                                              int* __restrict__ hist) {
  const int t = threadIdx.x, bx = blockIdx.x;
  if (bx == 0) {
    if (t < 64) {
      for (int p = 0; p < 16; p++) {
        const float v = anchors[p * 64 + t];
        const float n = sqrtf(wave_sum(v * v));
        anchT[t * 16 + p] = v / n;
      }
    }
  } else if (bx <= 256) {
    negparts[(bx - 1) * 256 + t] = 0.f;
  } else {
    hist[(bx - 257) * 256 + t] = 0;
  }
}

// compute j per row, histogram over j>>6 (2048 buckets)
__global__ __launch_bounds__(256) void k_mark(const int* __restrict__ labels,
                                              const int* __restrict__ negidx,
                                              int* __restrict__ jidx,
                                              int* __restrict__ hist) {
  const int i = blockIdx.x * 256 + threadIdx.x;
  if (i >= W_ROWS) return;
  int j;
  if (i < LBL_ROWS) { j = labels[i]; if (j < 0) j = 0; }
  else               { j = negidx[i - LBL_ROWS]; }
  jidx[i] = j;
  atomicAdd(&hist[j >> 6], 1);
}

// single-block exclusive scan of 2048-entry hist (8 per thread + Hillis-Steele)
__global__ __launch_bounds__(256) void k_scan(int* __restrict__ hist) {
  __shared__ int s[256];
  const int t = threadIdx.x;
  int v[8]; int sum = 0;
#pragma unroll
  for (int e = 0; e < 8; e++) { v[e] = hist[t * 8 + e]; sum += v[e]; }
  s[t] = sum; __syncthreads();
  for (int off = 1; off < 256; off <<= 1) {
    const int x = s[t];
    const int y = (t >= off) ? s[t - off] : 0;
    __syncthreads();
    s[t] = x + y;
    __syncthreads();
  }
  int run = s[t] - sum;  // exclusive prefix of this thread's chunk
#pragma unroll
  for (int e = 0; e < 8; e++) { hist[t * 8 + e] = run; run += v[e]; }
}

// scatter row ids into sorted-j order (hist holds running offsets)
__global__ __launch_bounds__(256) void k_scatter(const int* __restrict__ jidx,
                                                 int* __restrict__ hist,
                                                 int* __restrict__ sorted) {
  const int i = blockIdx.x * 256 + threadIdx.x;
  if (i >= W_ROWS) return;
  const int pos = atomicAdd(&hist[jidx[i] >> 6], 1);
  sorted[pos] = i;
}

__global__ __launch_bounds__(256) void k_query(const int* __restrict__ indices,
                                               const float* __restrict__ mask,
                                               const float* __restrict__ embed,
                                               const float* __restrict__ anchT,
                                               const float* __restrict__ omega,
                                               float* __restrict__ qcomp) {
  const int b = blockIdx.x, t = threadIdx.x;
  const int wv = t >> 6, ln = t & 63;
  __shared__ int sidx[L_SEQ];
  __shared__ float smask[L_SEQ];
  __shared__ float4 spart[256];
  __shared__ float smsum[4];
  __shared__ float sx[256];
  if (t < L_SEQ) { sidx[t] = indices[b * L_SEQ + t]; smask[t] = mask[b * L_SEQ + t]; }
  __syncthreads();
  float4 acc = {0.f, 0.f, 0.f, 0.f};
  float msum = 0.f;
#pragma unroll 8
  for (int l = wv * 32; l < wv * 32 + 32; l++) {
    const float m = smask[l];
    msum += m;
    const float4 e = *(const float4*)(embed + (size_t)sidx[l] * D_EMB + ln * 4);
    acc.x = fmaf(e.x, m, acc.x); acc.y = fmaf(e.y, m, acc.y);
    acc.z = fmaf(e.z, m, acc.z); acc.w = fmaf(e.w, m, acc.w);
  }
  spart[wv * 64 + ln] = acc;
  if (ln == 0) smsum[wv] = msum;
  __syncthreads();
  const float* spf = (const float*)spart;
  float q = spf[t] + spf[256 + t] + spf[512 + t] + spf[768 + t];
  const float mt = smsum[0] + smsum[1] + smsum[2] + smsum[3];
  q /= fmaxf(mt, 1.0f);
  const float ss = wave_sum(q * q);  // wave == head
  sx[t] = q / fmaxf(sqrtf(ss), 1e-4f);
  __syncthreads();
  slay_tail(sx, t, anchT, omega, qcomp + (size_t)b * CROW);
}

// 8 sorted-adjacent rows per block: clustered-j gather, LDS normalize,
// omega loaded once per 8 rows.
__global__ __launch_bounds__(256) void k_wrows(const int* __restrict__ sorted,
                                               const int* __restrict__ jidx,
                                               const float* __restrict__ kern,
                                               const float* __restrict__ anchT,
                                               const float* __restrict__ omega,
                                               float* __restrict__ wcomp) {
  __shared__ int sj[RPB];
  __shared__ int ssid[RPB];
  __shared__ float sx[RPB * 256];
  __shared__ float snorm[RPB * 4];
  const int tid = threadIdx.x;
  // XCD-contiguous remap: each XCD gets a contiguous sorted-j band (1280 = 8*160)
  const int cb = (blockIdx.x & 7) * 160 + (blockIdx.x >> 3);
  const int i0 = cb * RPB;

  if (tid < RPB) {
    const int sid = sorted[i0 + tid];
    ssid[tid] = sid;
    sj[tid] = jidx[sid];
  }
  __syncthreads();

  // gather 8 columns of kern (8 independent 64-line gathers in flight)
#pragma unroll
  for (int k = 0; k < RPB; k++) {
    const int idx = k * 256 + tid;
    sx[idx] = kern[(size_t)(idx & 255) * NLAB + sj[idx >> 8]];
  }
  __syncthreads();

  // per-(row,head) norms: 32 threads/row, 8 elems each, octet shuffle-reduce
  {
    const int row = tid >> 5, sub = tid & 31;
    const float* xp = sx + row * 256 + sub * 8;
    float ssum = 0.f;
#pragma unroll
    for (int e = 0; e < 8; e++) ssum = fmaf(xp[e], xp[e], ssum);
    ssum += __shfl_xor(ssum, 1, 64);
    ssum += __shfl_xor(ssum, 2, 64);
    ssum += __shfl_xor(ssum, 4, 64);
    if ((sub & 7) == 0) snorm[row * 4 + (sub >> 3)] = fmaxf(sqrtf(ssum), 1e-4f);
  }
  __syncthreads();
#pragma unroll
  for (int k = 0; k < RPB; k++) {
    const int idx = k * 256 + tid;
    sx[idx] /= snorm[(idx >> 8) * 4 + ((idx >> 6) & 3)];
  }
  __syncthreads();

  // prf: thread = (r,h,m); omega element loaded once, used for 8 rows
  {
    const int h = (tid >> 5) & 3, r = tid >> 7;
    const float* om = omega + (size_t)(tid >> 5) * 2048 + (tid & 31);
    float acc[RPB];
#pragma unroll
    for (int row = 0; row < RPB; row++) acc[row] = 0.f;
#pragma unroll
    for (int dd = 0; dd < 64; dd += 2) {
      const float o0 = om[dd * 32], o1 = om[dd * 32 + 32];
#pragma unroll
      for (int row = 0; row < RPB; row++) {
        const float2 xv = *(const float2*)(sx + row * 256 + h * 64 + dd);
        acc[row] = fmaf(xv.x, o0, fmaf(xv.y, o1, acc[row]));
      }
    }
    const float s = r ? 1.70710592763316f : 0.29289307236691f;
    const float w = r ? 0.07322326809171f : 0.42677648190829f;
    const float sc = sqrtf(2.0f * s);
    const float outs = sqrtf(w) / sqrtf(32.000001f);
#pragma unroll
    for (int row = 0; row < RPB; row++) {
      float arg = acc[row] * 0.125f * sc - s;
      arg = fminf(fmaxf(arg, -20.0f), 20.0f);
      wcomp[(size_t)ssid[row] * CROW + 64 + tid] = expf(arg) * outs;
    }
  }

  // poly: thread = (hp, rowpair); 2 rows each
  {
    const int hp = tid & 63, rp = tid >> 6;
    const int h = hp >> 4, p = hp & 15;
    const float* x0 = sx + (rp * 2) * 256 + h * 64;
    const float* x1 = x0 + 256;
    float d0 = 0.f, d1 = 0.f;
#pragma unroll
    for (int dd = 0; dd < 64; dd++) {
      const float a = anchT[dd * 16 + p];
      d0 = fmaf(x0[dd], a, d0);
      d1 = fmaf(x1[dd], a, d1);
    }
    d0 = fminf(fmaxf(d0, -1.0f), 1.0f);
    d1 = fminf(fmaxf(d1, -1.0f), 1.0f);
    wcomp[(size_t)ssid[rp * 2] * CROW + h * 16 + p]     = d0 * d0 * 0.25f;
    wcomp[(size_t)ssid[rp * 2 + 1] * CROW + h * 16 + p] = d1 * d1 * 0.25f;
  }
}

// neg partial sums: grid (16 qtiles, 64 wtiles, 4 heads), 128 thr. (R2 version)
__global__ __launch_bounds__(128) void k_neg(const float* __restrict__ qcomp,
                                             const float* __restrict__ wcomp,
                                             float* __restrict__ negparts) {
  __shared__ float qt[64 * LST];
  __shared__ float wt[32 * LST];
  const int tid = threadIdx.x;
  const int qb0 = blockIdx.x * 64;
  const int wr0 = LBL_ROWS + blockIdx.y * 32;
  const int h = blockIdx.z;

  for (int idx = tid; idx < 96 * 20; idx += 128) {
    const int row = idx / 20, c4 = idx % 20;
    int col, lcol;
    if (c4 < 4)       { col = h * 16 + c4 * 4;              lcol = c4 * 4; }
    else if (c4 < 12) { col = 64 + h * 32 + (c4 - 4) * 4;   lcol = 16 + (c4 - 4) * 4; }
    else              { col = 192 + h * 32 + (c4 - 12) * 4; lcol = 48 + (c4 - 12) * 4; }
    const bool isq = row < 64;
    const int grow = isq ? (qb0 + row) : (wr0 + row - 64);
    const float4 v = *(const float4*)((isq ? qcomp : wcomp) + (size_t)grow * CROW + col);
    float* dst = (isq ? qt + row * LST : wt + (row - 64) * LST) + lcol;
    dst[0] = v.x; dst[1] = v.y; dst[2] = v.z; dst[3] = v.w;
  }
  __syncthreads();

  const int qg = tid >> 3;
  const int wg = tid & 7;
  const float* qb = qt + (qg * 4) * LST;
  const float* wb = wt + (wg * 4) * LST;

  float pd[4][4] = {{0.f}}, pf[4][4] = {{0.f}};
#pragma unroll
  for (int kc = 0; kc < 8; kc++) {
    float2 qv[4], wv[4];
#pragma unroll
    for (int i = 0; i < 4; i++) qv[i] = *(const float2*)(qb + i * LST + 2 * kc);
#pragma unroll
    for (int j = 0; j < 4; j++) wv[j] = *(const float2*)(wb + j * LST + 2 * kc);
#pragma unroll
    for (int i = 0; i < 4; i++)
#pragma unroll
      for (int j = 0; j < 4; j++) {
        pd[i][j] = fmaf(qv[i].x, wv[j].x, pd[i][j]);
        pd[i][j] = fmaf(qv[i].y, wv[j].y, pd[i][j]);
      }
  }
#pragma unroll 8
  for (int kc = 0; kc < 32; kc++) {
    float2 qv[4], wv[4];
#pragma unroll
    for (int i = 0; i < 4; i++) qv[i] = *(const float2*)(qb + i * LST + 16 + 2 * kc);
#pragma unroll
    for (int j = 0; j < 4; j++) wv[j] = *(const float2*)(wb + j * LST + 16 + 2 * kc);
#pragma unroll
    for (int i = 0; i < 4; i++)
#pragma unroll
      for (int j = 0; j < 4; j++) {
        pf[i][j] = fmaf(qv[i].x, wv[j].x, pf[i][j]);
        pf[i][j] = fmaf(qv[i].y, wv[j].y, pf[i][j]);
      }
  }

#pragma unroll
  for (int i = 0; i < 4; i++) {
    float acc = 0.f;
#pragma unroll
    for (int j = 0; j < 4; j++) acc += pd[i][j] * pf[i][j];
#pragma unroll
    for (int off = 1; off < 8; off <<= 1) acc += __shfl_xor(acc, off, 64);
    if (wg == 0) atomicAdd(&negparts[blockIdx.y * B_Q + qb0 + qg * 4 + i], acc);
  }
}

__global__ __launch_bounds__(256) void k_pos(const float* __restrict__ qcomp,
                                             const float* __restrict__ wcomp,
                                             float* __restrict__ pos) {
  const int tid = threadIdx.x;
  const int g = blockIdx.x * 64 + (tid >> 2);
  const int h = tid & 3;
  const float* q = qcomp + (size_t)(g >> 3) * CROW;
  const float* w = wcomp + (size_t)g * CROW;
  float pd = 0.f, pf = 0.f;
#pragma unroll
  for (int c = 0; c < 4; c++) {
    const float4 qv = *(const float4*)(q + h * 16 + c * 4);
    const float4 wv = *(const float4*)(w + h * 16 + c * 4);
    pd += qv.x * wv.x + qv.y * wv.y + qv.z * wv.z + qv.w * wv.w;
  }
#pragma unroll
  for (int r = 0; r < 2; r++)
#pragma unroll
    for (int c = 0; c < 8; c++) {
      const float4 qv = *(const float4*)(q + 64 + r * 128 + h * 32 + c * 4);
      const float4 wv = *(const float4*)(w + 64 + r * 128 + h * 32 + c * 4);
      pf += qv.x * wv.x + qv.y * wv.y + qv.z * wv.z + qv.w * wv.w;
    }
  float sc = pd * pf;
  sc += __shfl_xor(sc, 1, 64);
  sc += __shfl_xor(sc, 2, 64);
  if (h == 0) pos[g] = sc;
}

__global__ __launch_bounds__(1024) void k_loss(const float* __restrict__ pos,
                                               const float* __restrict__ negparts,
                                               const float* __restrict__ lmask,
                                               float* __restrict__ out) {
  const int b = threadIdx.x;
  float lp[8];
  float possum = 0.f;
#pragma unroll
  for (int k = 0; k < 8; k++) { lp[k] = pos[b * 8 + k]; possum += lp[k]; }
  float negsum = 0.f;
#pragma unroll 8
  for (int c = 0; c < 64; c++) negsum += negparts[c * B_Q + b];
  const float Z = possum + negsum + 2.056e-5f;  // + 2056 * 1e-8
  const float logZ = logf(Z);
  float local = 0.f, lsum = 0.f;
#pragma unroll
  for (int k = 0; k < 8; k++) {
    const float lm = lmask[b * 8 + k];
    local += lm * (logf(lp[k] + 1e-8f) - logZ);
    lsum += lm;
  }
  local = wave_sum(local);
  lsum = wave_sum(lsum);
  __shared__ float r1[16], r2[16];
  const int wid = b >> 6;
  if ((b & 63) == 0) { r1[wid] = local; r2[wid] = lsum; }
  __syncthreads();
  if (b == 0) {
    float t1 = 0.f, t2 = 0.f;
    for (int wv = 0; wv < 16; wv++) { t1 += r1[wv]; t2 += r2[wv]; }
    out[0] = -t1 / (t2 + 1e-6f);
  }
}

extern "C" void kernel_launch(void* const* d_in, const int* in_sizes, int n_in,
                              void* d_out, int out_size, void* d_ws, size_t ws_size,
                              hipStream_t stream) {
  const int* indices  = (const int*)d_in[0];
  const float* mask   = (const float*)d_in[1];
  const int* labels   = (const int*)d_in[2];
  const float* lmask  = (const float*)d_in[3];
  const int* negidx   = (const int*)d_in[4];
  const float* embed  = (const float*)d_in[5];
  const float* kern   = (const float*)d_in[6];
  const float* omega  = (const float*)d_in[7];
  const float* anchors= (const float*)d_in[8];
  float* out = (float*)d_out;

  float* ws = (float*)d_ws;
  float* anchT    = ws;                            // 1024
  float* qcomp    = anchT + 1024;                  // 1024*320
  float* wcomp    = qcomp + (size_t)B_Q * CROW;    // 10240*320
  float* pos      = wcomp + (size_t)W_ROWS * CROW; // 8192
  float* negparts = pos + LBL_ROWS;                // 64*1024
  int*   jidx     = (int*)(negparts + 64 * B_Q);   // 10240
  int*   sorted   = jidx + W_ROWS;                 // 10240
  int*   hist     = sorted + W_ROWS;               // 2048

  k_prep<<<265, 256, 0, stream>>>(anchors, anchT, negparts, hist);
  k_mark<<<40, 256, 0, stream>>>(labels, negidx, jidx, hist);
  k_scan<<<1, 256, 0, stream>>>(hist);
  k_scatter<<<40, 256, 0, stream>>>(jidx, hist, sorted);
  k_query<<<B_Q, 256, 0, stream>>>(indices, mask, embed, anchT, omega, qcomp);
  k_wrows<<<W_ROWS / RPB, 256, 0, stream>>>(sorted, jidx, kern, anchT, omega, wcomp);
  k_neg<<<dim3(16, 64, 4), 128, 0, stream>>>(qcomp, wcomp, negparts);
  k_pos<<<128, 256, 0, stream>>>(qcomp, wcomp, pos);
  k_loss<<<1, 1024, 0, stream>>>(pos, negparts, lmask, out);
}